// Round 15
// baseline (536.885 us; speedup 1.0000x reference)
//
#include <hip/hip_runtime.h>
#include <hip/hip_bf16.h>
#include <math.h>

typedef __attribute__((ext_vector_type(8))) short bf16x8;
typedef __attribute__((ext_vector_type(4))) float f32x4;

__device__ inline unsigned f2bf(float f) {
    union { __hip_bfloat16 h; unsigned short u; } cv;
    cv.h = __float2bfloat16(f);
    return (unsigned)cv.u;
}
__device__ inline float bfu(unsigned u) {          // bf16 bits -> float
    return __uint_as_float(u << 16);
}

// ---------------- CSR construction ----------------

__global__ void k_hist(const int* __restrict__ dst, int* __restrict__ counts, int E) {
    int e = blockIdx.x * blockDim.x + threadIdx.x;
    if (e < E) atomicAdd(&counts[dst[e]], 1);
}

__global__ void k_scan1(const int* __restrict__ counts, int* __restrict__ row_ptr,
                        int* __restrict__ csum, int n) {
    __shared__ int buf[1024];
    int tid = threadIdx.x;
    int base = blockIdx.x * 1024;
    int v = (base + tid < n) ? counts[base + tid] : 0;
    buf[tid] = v;
    __syncthreads();
    int inc = v;
    for (int off = 1; off < 1024; off <<= 1) {
        int add = (tid >= off) ? buf[tid - off] : 0;
        __syncthreads();
        inc += add;
        buf[tid] = inc;
        __syncthreads();
    }
    if (base + tid < n) row_ptr[base + tid] = inc - v;
    if (tid == 1023) csum[blockIdx.x] = inc;
}

__global__ void k_scan2(int* __restrict__ csum, int nc, int* __restrict__ total) {
    if (threadIdx.x == 0) {
        int run = 0;
        for (int i = 0; i < nc; ++i) { int c = csum[i]; csum[i] = run; run += c; }
        *total = run;
    }
}

__global__ void k_scan3(int* __restrict__ row_ptr, const int* __restrict__ csum,
                        const int* __restrict__ total, int n) {
    int i = blockIdx.x * blockDim.x + threadIdx.x;
    if (i < n) row_ptr[i] += csum[i >> 10];
    if (i == 0) row_ptr[n] = *total;
}

// ---------------- Two-phase bucketed scatter ----------------
// 64 dst-range buckets; staging regions = exact CSR bucket regions (base row_ptr[b*NS64]).
// Phase 1: LDS histogram + per-(block,bucket) reservation -> sequential staging runs.
// Pack: src (24b) | dloc (16b) | eid (24b).  Requires N < 2^24, NS64 < 2^16, E < 2^24.

#define ECH2 4096
__global__ __launch_bounds__(256) void k_part(const int* __restrict__ src,
        const int* __restrict__ dst, const int* __restrict__ row_ptr,
        int* __restrict__ bfill, unsigned long long* __restrict__ staging,
        int E, int NS64, int N) {
    __shared__ int lh[64], lbase[64], lfill[64];
    int tid = threadIdx.x;
    if (tid < 64) lh[tid] = 0;
    __syncthreads();
    int base = blockIdx.x * ECH2;
#pragma unroll 1
    for (int j = 0; j < ECH2 / 256; ++j) {
        int e = base + j * 256 + tid;
        if (e < E) atomicAdd(&lh[dst[e] / NS64], 1);
    }
    __syncthreads();
    if (tid < 64) {
        int bs = row_ptr[min(tid * NS64, N)];
        lbase[tid] = bs + atomicAdd(&bfill[tid], lh[tid]);
        lfill[tid] = 0;
    }
    __syncthreads();
#pragma unroll 1
    for (int j = 0; j < ECH2 / 256; ++j) {
        int e = base + j * 256 + tid;
        if (e < E) {
            int d = dst[e];
            int b = d / NS64;
            int r = atomicAdd(&lfill[b], 1);
            unsigned long long pk = (unsigned long long)((unsigned)src[e] & 0xffffffu)
                | ((unsigned long long)((unsigned)(d - b * NS64) & 0xffffu) << 24)
                | ((unsigned long long)(unsigned)e << 40);
            staging[lbase[b] + r] = pk;
        }
    }
}

// Phase 2: 2 blocks per bucket; scatter confined to the bucket's L2-resident region.
__global__ __launch_bounds__(256) void k_scat2(const unsigned long long* __restrict__ staging,
        const int* __restrict__ row_ptr, int* __restrict__ fill,
        int2* __restrict__ spe, int NS64, int N) {
    int b = blockIdx.x >> 1;
    int half = blockIdx.x & 1;
    int s0 = row_ptr[min(b * NS64, N)];
    int s1 = row_ptr[min((b + 1) * NS64, N)];
    int cnt = s1 - s0;
    int h0 = cnt >> 1;
    int start = s0 + (half ? h0 : 0);
    int len = half ? (cnt - h0) : h0;
    for (int i = threadIdx.x; i < len; i += 256) {
        unsigned long long pk = staging[start + i];
        int srcv = (int)(pk & 0xffffffu);
        int dloc = (int)((pk >> 24) & 0xffffu);
        int eid  = (int)(pk >> 40);
        int d = b * NS64 + dloc;
        int pos = row_ptr[d] + atomicAdd(&fill[d], 1);
        spe[pos] = make_int2(srcv, eid);
    }
}

__global__ void k_gptr(const int* __restrict__ batch, int* __restrict__ gptr, int n, int G) {
    int i = blockIdx.x * blockDim.x + threadIdx.x;
    if (i > n) return;
    if (i == 0) {
        int b0 = batch[0];
        for (int g = 0; g <= b0; ++g) gptr[g] = 0;
    } else if (i == n) {
        int bl = batch[n - 1];
        for (int g = bl + 1; g <= G; ++g) gptr[g] = n;
    } else {
        int b = batch[i], pb = batch[i - 1];
        for (int g = pb + 1; g <= b; ++g) gptr[g] = i;
    }
}

// ---------------- weight prep ----------------
// bond: W1b bf16 [64 col][16 k], W2tb bf16 [64 n][64 k]

__global__ void k_wt(const float* __restrict__ W1, const float* __restrict__ W2,
                     unsigned short* __restrict__ W1b, unsigned short* __restrict__ W2tb) {
    int tid = blockIdx.x * blockDim.x + threadIdx.x;
    if (tid < 1024) {
        int j = tid / 16, k = tid % 16;
        W1b[j * 16 + k] = (unsigned short)f2bf(W1[k * 64 + j]);
    }
    if (tid < 4096) {
        int j = tid / 64, k = tid % 64;
        W2tb[j * 64 + k] = (unsigned short)f2bf(W2[k * 64 + j]);
    }
}

// conv: W1tb bf16 [L][128 n][64 k], W2tb bf16 [L][64 n][128 k]
__global__ void k_wtc(const float* __restrict__ W1, const float* __restrict__ W2,
                      unsigned short* __restrict__ W1tb, unsigned short* __restrict__ W2tb,
                      int L) {
    int idx = blockIdx.x * blockDim.x + threadIdx.x;
    int tot = L * 8192;
    if (idx < tot) {
        int l = idx / 8192, r = idx % 8192;
        int j = r / 64, k = r % 64;
        W1tb[(long)l * 8192 + j * 64 + k] = (unsigned short)f2bf(W1[(long)l * 8192 + k * 128 + j]);
        int j2 = r / 128, k2 = r % 128;
        W2tb[(long)l * 8192 + j2 * 128 + k2] =
            (unsigned short)f2bf(W2[(long)l * 8192 + k2 * 64 + j2]);
    }
}

// ---------------- Atom encoder: [M,32] -> relu -> [M,64] -> relu (+ bf16 copy) ----------

#define TM 128
__global__ __launch_bounds__(256) void k_atom(const float* __restrict__ x,
        const float* __restrict__ W1, const float* __restrict__ b1,
        const float* __restrict__ W2, const float* __restrict__ b2,
        float* __restrict__ out, unsigned short* __restrict__ hb, int M) {
    __shared__ float sU[TM * 65];
    __shared__ float sW1[32 * 64];
    __shared__ float sW2[64 * 64];
    __shared__ float sB1[64], sB2[64];
#define A_IN(r, c) sU[(r) * 33 + (c)]
#define A_T1(r, c) sU[(r) * 65 + (c)]
    int tid = threadIdx.x;
    int base = blockIdx.x * TM;
    for (int i = tid; i < 32 * 64 / 4; i += 256) ((float4*)sW1)[i] = ((const float4*)W1)[i];
    for (int i = tid; i < 64 * 64 / 4; i += 256) ((float4*)sW2)[i] = ((const float4*)W2)[i];
    if (tid < 64) { sB1[tid] = b1[tid]; sB2[tid] = b2[tid]; }
    for (int i = tid; i < TM * 32 / 4; i += 256) {
        int r = i / 8, c4 = i % 8;
        int row = base + r;
        float4 v = (row < M) ? ((const float4*)(x + (long)row * 32))[c4] : make_float4(0, 0, 0, 0);
        A_IN(r, c4 * 4 + 0) = v.x; A_IN(r, c4 * 4 + 1) = v.y;
        A_IN(r, c4 * 4 + 2) = v.z; A_IN(r, c4 * 4 + 3) = v.w;
    }
    __syncthreads();
    int r0 = (tid / 16) * 8;
    int c0 = (tid % 16) * 4;
    float acc[8][4];
#pragma unroll
    for (int i = 0; i < 8; i++)
#pragma unroll
        for (int j = 0; j < 4; j++) acc[i][j] = sB1[c0 + j];
    for (int k = 0; k < 32; k++) {
        float a[8], b[4];
#pragma unroll
        for (int i = 0; i < 8; i++) a[i] = A_IN(r0 + i, k);
#pragma unroll
        for (int j = 0; j < 4; j++) b[j] = sW1[k * 64 + c0 + j];
#pragma unroll
        for (int i = 0; i < 8; i++)
#pragma unroll
            for (int j = 0; j < 4; j++) acc[i][j] += a[i] * b[j];
    }
    __syncthreads();
#pragma unroll
    for (int i = 0; i < 8; i++)
#pragma unroll
        for (int j = 0; j < 4; j++) A_T1(r0 + i, c0 + j) = fmaxf(acc[i][j], 0.f);
    __syncthreads();
#pragma unroll
    for (int i = 0; i < 8; i++)
#pragma unroll
        for (int j = 0; j < 4; j++) acc[i][j] = sB2[c0 + j];
    for (int k = 0; k < 64; k++) {
        float a[8], b[4];
#pragma unroll
        for (int i = 0; i < 8; i++) a[i] = A_T1(r0 + i, k);
#pragma unroll
        for (int j = 0; j < 4; j++) b[j] = sW2[k * 64 + c0 + j];
#pragma unroll
        for (int i = 0; i < 8; i++)
#pragma unroll
            for (int j = 0; j < 4; j++) acc[i][j] += a[i] * b[j];
    }
#pragma unroll
    for (int i = 0; i < 8; i++) {
        int row = base + r0 + i;
        if (row < M) {
            float4 v = make_float4(fmaxf(acc[i][0], 0.f), fmaxf(acc[i][1], 0.f),
                                   fmaxf(acc[i][2], 0.f), fmaxf(acc[i][3], 0.f));
            *(float4*)(out + (long)row * 64 + c0) = v;
            unsigned p01 = f2bf(v.x) | (f2bf(v.y) << 16);
            unsigned p23 = f2bf(v.z) | (f2bf(v.w) << 16);
            *(uint2*)(hb + (long)row * 64 + c0) = make_uint2(p01, p23);
        }
    }
}

// ---------------- Bond encoder: BOTH layers via MFMA; layer1 swapped (D=[ch][edge]) ----

__global__ __launch_bounds__(256) void k_bond(const float* __restrict__ ea,
        const int2* __restrict__ spe,
        const unsigned short* __restrict__ W1b, const float* __restrict__ b1,
        const unsigned short* __restrict__ W2tb, const float* __restrict__ b2,
        unsigned short* __restrict__ e_q, int E) {
    __shared__ unsigned sT1[128 * 32];   // bf16[128][64], pair-swizzled
    __shared__ unsigned sW2[64 * 32];    // bf16[64][64] (W2^T), pair-swizzled
    int tid = threadIdx.x;

    for (int i = tid; i < 2048; i += 256) {
        int rw = i >> 5, cp = i & 31;
        sW2[rw * 32 + (cp ^ ((rw & 7) << 2))] = ((const unsigned*)W2tb)[i];
    }

    int wv = tid >> 6, lane = tid & 63;
    int lr = lane & 15, q = lane >> 4;

    // layer-1 A-fragments (W1, m=channel) + per-element bias (channel = nt*16+4q+i)
    union { bf16x8 v; uint4 u4; } bf1[4];
    float4 bias1[4];
#pragma unroll
    for (int nt = 0; nt < 4; ++nt) {
        bf1[nt].u4 = make_uint4(0, 0, 0, 0);
        if (q < 2)
            bf1[nt].u4 = *(const uint4*)(W1b + (nt * 16 + lr) * 16 + q * 8);
        bias1[nt] = *(const float4*)(b1 + nt * 16 + q * 4);
    }

#pragma unroll
    for (int mt1 = 0; mt1 < 2; ++mt1) {
        int rtile = wv * 2 + mt1;
        long row1 = (long)blockIdx.x * 128 + rtile * 16 + lr;
        long eidx = row1 < (long)E ? row1 : (long)(E - 1);
        int eid = spe[eidx].y;
        union { bf16x8 v; uint4 u4; unsigned u[4]; } af1;   // B operand: col=edge
        af1.u4 = make_uint4(0, 0, 0, 0);
        if (q < 2) {
            const float4* er = (const float4*)(ea + (long)eid * 16 + q * 8);
            float4 u0 = er[0], u1 = er[1];
            af1.u[0] = f2bf(u0.x) | (f2bf(u0.y) << 16);
            af1.u[1] = f2bf(u0.z) | (f2bf(u0.w) << 16);
            af1.u[2] = f2bf(u1.x) | (f2bf(u1.y) << 16);
            af1.u[3] = f2bf(u1.z) | (f2bf(u1.w) << 16);
        }
        int r = rtile * 16 + lr;            // edge row in sT1
#pragma unroll
        for (int nt = 0; nt < 4; ++nt) {
            f32x4 c0;
            c0[0] = bias1[nt].x; c0[1] = bias1[nt].y;
            c0[2] = bias1[nt].z; c0[3] = bias1[nt].w;
            f32x4 d = __builtin_amdgcn_mfma_f32_16x16x32_bf16(bf1[nt].v, af1.v, c0, 0, 0, 0);
            unsigned p01 = f2bf(fmaxf(d[0], 0.f)) | (f2bf(fmaxf(d[1], 0.f)) << 16);
            unsigned p23 = f2bf(fmaxf(d[2], 0.f)) | (f2bf(fmaxf(d[3], 0.f)) << 16);
            int cp = nt * 8 + q * 2;
            sT1[r * 32 + (cp ^ ((r & 7) << 2))] = p01;
            sT1[r * 32 + ((cp + 1) ^ ((r & 7) << 2))] = p23;
        }
    }
    __syncthreads();

    bf16x8 bf[4][2];
#pragma unroll
    for (int nt = 0; nt < 4; ++nt)
#pragma unroll
        for (int ks = 0; ks < 2; ++ks) {
            int rw = nt * 16 + lr;
            int u = rw * 32 + ((ks * 16 + q * 4) ^ ((rw & 7) << 2));
            bf[nt][ks] = *(const bf16x8*)&sW2[u];
        }
    f32x4 acc[2][4];
#pragma unroll
    for (int mt = 0; mt < 2; ++mt)
#pragma unroll
        for (int nt = 0; nt < 4; ++nt) {
            float bias = b2[nt * 16 + lr];
            f32x4 c0; c0[0] = bias; c0[1] = bias; c0[2] = bias; c0[3] = bias;
            acc[mt][nt] = c0;
        }
#pragma unroll
    for (int mt = 0; mt < 2; ++mt) {
        int rw = (wv * 2 + mt) * 16 + lr;
#pragma unroll
        for (int ks = 0; ks < 2; ++ks) {
            int u = rw * 32 + ((ks * 16 + q * 4) ^ ((rw & 7) << 2));
            bf16x8 af = *(const bf16x8*)&sT1[u];
#pragma unroll
            for (int nt = 0; nt < 4; ++nt)
                acc[mt][nt] = __builtin_amdgcn_mfma_f32_16x16x32_bf16(
                    af, bf[nt][ks], acc[mt][nt], 0, 0, 0);
        }
    }
#pragma unroll
    for (int mt = 0; mt < 2; ++mt)
#pragma unroll
        for (int nt = 0; nt < 4; ++nt) {
            long r0 = (long)blockIdx.x * 128 + (wv * 2 + mt) * 16 + q * 4;
            unsigned p01 = f2bf(fmaxf(acc[mt][nt][0], 0.f)) |
                           (f2bf(fmaxf(acc[mt][nt][1], 0.f)) << 16);
            unsigned p23 = f2bf(fmaxf(acc[mt][nt][2], 0.f)) |
                           (f2bf(fmaxf(acc[mt][nt][3], 0.f)) << 16);
            long qb = ((r0 >> 2) * 64 + nt * 16 + lr) * 4;
            if (r0 + 3 < (long)E) {
                *(uint2*)(e_q + qb) = make_uint2(p01, p23);
            } else {
                unsigned vv[4] = {p01 & 0xffff, p01 >> 16, p23 & 0xffff, p23 >> 16};
#pragma unroll
                for (int i = 0; i < 4; ++i)
                    if (r0 + i < (long)E) e_q[qb + i] = (unsigned short)vv[i];
            }
        }
}

// ---------------- Aggregation: bf16 h gathers, 8-wide online softmax; y out bf16 -------

__global__ __launch_bounds__(256) void k_agg(const float* __restrict__ h,
        const unsigned short* __restrict__ h_bf,
        const unsigned short* __restrict__ e_q, const int2* __restrict__ spe,
        const int* __restrict__ row_ptr, const float* __restrict__ t_ptr, int layer,
        unsigned short* __restrict__ yb, int n) {
    int wid = blockIdx.x * 4 + (threadIdx.x >> 6);
    int lane = threadIdx.x & 63;
    if (wid >= n) return;
    wid = __builtin_amdgcn_readfirstlane(wid);
    float tval = t_ptr[layer];
    int beg = row_ptr[wid], end = row_ptr[wid + 1];
    float m = -INFINITY, den = 0.f, num = 0.f;
    int i = beg;
    int astart = (beg + 3) & ~3; if (astart > end) astart = end;
    int aend = end & ~3;         if (aend < astart) aend = astart;
    for (; i < astart; ++i) {
        int s = spe[i].x;
        float ev = bfu((unsigned)e_q[((long)(i >> 2) * 64 + lane) * 4 + (i & 3)]);
        float hv = bfu((unsigned)h_bf[(long)s * 64 + lane]);
        float msg = fmaxf(hv + ev, 0.f) + 1e-7f;
        float sv = msg * tval;
        float mn = fmaxf(m, sv);
        float sc = __expf(m - mn);
        float w = __expf(sv - mn);
        den = den * sc + w;
        num = num * sc + w * msg;
        m = mn;
    }
    for (; i + 8 <= aend; i += 8) {
        int s0 = spe[i].x,     s1 = spe[i + 1].x, s2 = spe[i + 2].x, s3 = spe[i + 3].x;
        int s4 = spe[i + 4].x, s5 = spe[i + 5].x, s6 = spe[i + 6].x, s7 = spe[i + 7].x;
        uint2 ea0 = *(const uint2*)(e_q + ((long)(i >> 2) * 64 + lane) * 4);
        uint2 ea1 = *(const uint2*)(e_q + ((long)((i >> 2) + 1) * 64 + lane) * 4);
        float hv0 = bfu((unsigned)h_bf[(long)s0 * 64 + lane]);
        float hv1 = bfu((unsigned)h_bf[(long)s1 * 64 + lane]);
        float hv2 = bfu((unsigned)h_bf[(long)s2 * 64 + lane]);
        float hv3 = bfu((unsigned)h_bf[(long)s3 * 64 + lane]);
        float hv4 = bfu((unsigned)h_bf[(long)s4 * 64 + lane]);
        float hv5 = bfu((unsigned)h_bf[(long)s5 * 64 + lane]);
        float hv6 = bfu((unsigned)h_bf[(long)s6 * 64 + lane]);
        float hv7 = bfu((unsigned)h_bf[(long)s7 * 64 + lane]);
        float msg0 = fmaxf(hv0 + bfu(ea0.x & 0xffff), 0.f) + 1e-7f;
        float msg1 = fmaxf(hv1 + bfu(ea0.x >> 16), 0.f) + 1e-7f;
        float msg2 = fmaxf(hv2 + bfu(ea0.y & 0xffff), 0.f) + 1e-7f;
        float msg3 = fmaxf(hv3 + bfu(ea0.y >> 16), 0.f) + 1e-7f;
        float msg4 = fmaxf(hv4 + bfu(ea1.x & 0xffff), 0.f) + 1e-7f;
        float msg5 = fmaxf(hv5 + bfu(ea1.x >> 16), 0.f) + 1e-7f;
        float msg6 = fmaxf(hv6 + bfu(ea1.y & 0xffff), 0.f) + 1e-7f;
        float msg7 = fmaxf(hv7 + bfu(ea1.y >> 16), 0.f) + 1e-7f;
        float sv0 = msg0 * tval, sv1 = msg1 * tval, sv2 = msg2 * tval, sv3 = msg3 * tval;
        float sv4 = msg4 * tval, sv5 = msg5 * tval, sv6 = msg6 * tval, sv7 = msg7 * tval;
        float mn = fmaxf(fmaxf(fmaxf(fmaxf(m, sv0), fmaxf(sv1, sv2)),
                               fmaxf(fmaxf(sv3, sv4), fmaxf(sv5, sv6))), sv7);
        float sc = __expf(m - mn);
        float w0 = __expf(sv0 - mn), w1 = __expf(sv1 - mn);
        float w2 = __expf(sv2 - mn), w3 = __expf(sv3 - mn);
        float w4 = __expf(sv4 - mn), w5 = __expf(sv5 - mn);
        float w6 = __expf(sv6 - mn), w7 = __expf(sv7 - mn);
        den = den * sc + (((w0 + w1) + (w2 + w3)) + ((w4 + w5) + (w6 + w7)));
        num = num * sc + (((w0 * msg0 + w1 * msg1) + (w2 * msg2 + w3 * msg3)) +
                          ((w4 * msg4 + w5 * msg5) + (w6 * msg6 + w7 * msg7)));
        m = mn;
    }
    for (; i < aend; i += 4) {
        int s0 = spe[i].x, s1 = spe[i + 1].x, s2 = spe[i + 2].x, s3 = spe[i + 3].x;
        uint2 ee = *(const uint2*)(e_q + ((long)(i >> 2) * 64 + lane) * 4);
        float hv0 = bfu((unsigned)h_bf[(long)s0 * 64 + lane]);
        float hv1 = bfu((unsigned)h_bf[(long)s1 * 64 + lane]);
        float hv2 = bfu((unsigned)h_bf[(long)s2 * 64 + lane]);
        float hv3 = bfu((unsigned)h_bf[(long)s3 * 64 + lane]);
        float msg0 = fmaxf(hv0 + bfu(ee.x & 0xffff), 0.f) + 1e-7f;
        float msg1 = fmaxf(hv1 + bfu(ee.x >> 16), 0.f) + 1e-7f;
        float msg2 = fmaxf(hv2 + bfu(ee.y & 0xffff), 0.f) + 1e-7f;
        float msg3 = fmaxf(hv3 + bfu(ee.y >> 16), 0.f) + 1e-7f;
        float sv0 = msg0 * tval, sv1 = msg1 * tval;
        float sv2 = msg2 * tval, sv3 = msg3 * tval;
        float mn = fmaxf(fmaxf(fmaxf(m, sv0), fmaxf(sv1, sv2)), sv3);
        float sc = __expf(m - mn);
        float w0 = __expf(sv0 - mn);
        float w1 = __expf(sv1 - mn);
        float w2 = __expf(sv2 - mn);
        float w3 = __expf(sv3 - mn);
        den = den * sc + ((w0 + w1) + (w2 + w3));
        num = num * sc + ((w0 * msg0 + w1 * msg1) + (w2 * msg2 + w3 * msg3));
        m = mn;
    }
    for (; i < end; ++i) {
        int s = spe[i].x;
        float ev = bfu((unsigned)e_q[((long)(i >> 2) * 64 + lane) * 4 + (i & 3)]);
        float hv = bfu((unsigned)h_bf[(long)s * 64 + lane]);
        float msg = fmaxf(hv + ev, 0.f) + 1e-7f;
        float sv = msg * tval;
        float mn = fmaxf(m, sv);
        float sc = __expf(m - mn);
        float w = __expf(sv - mn);
        den = den * sc + w;
        num = num * sc + w * msg;
        m = mn;
    }
    float agg = (end > beg) ? num / (den + 1e-16f) : 0.f;
    yb[(long)wid * 64 + lane] = (unsigned short)f2bf(h[(long)wid * 64 + lane] + agg);
}

// ---------------- GEMM1 (MFMA): yb[N,64]bf16 @ W1tb -> h1b[N,128]bf16 + BN partials ----

__global__ __launch_bounds__(256) void k_gemm1(const unsigned* __restrict__ yb,
        const unsigned* __restrict__ W1tb, const float* __restrict__ b1,
        unsigned* __restrict__ h1b, float* __restrict__ part, int n) {
    __shared__ unsigned sY[128 * 32];
    __shared__ unsigned sW[128 * 32];
    int tid = threadIdx.x;
    int base = blockIdx.x * 128;
    for (int i = tid; i < 4096; i += 256) {
        int rw = i >> 5, cp = i & 31;
        sW[rw * 32 + (cp ^ ((rw & 7) << 2))] = W1tb[i];
    }
#pragma unroll
    for (int j = 0; j < 16; ++j) {
        int u = j * 256 + tid;
        int r = u >> 5, cp = u & 31;
        long row = base + r;
        unsigned v = (row < (long)n) ? yb[row * 32 + cp] : 0u;
        sY[r * 32 + (cp ^ ((r & 7) << 2))] = v;
    }
    __syncthreads();
    int wv = tid >> 6, lane = tid & 63, lr = lane & 15, q = lane >> 4;
    bf16x8 bf[2][2];
    float bias[2];
#pragma unroll
    for (int nt2 = 0; nt2 < 2; ++nt2) {
        int rw = wv * 32 + nt2 * 16 + lr;
#pragma unroll
        for (int ks = 0; ks < 2; ++ks)
            bf[nt2][ks] = *(const bf16x8*)&sW[rw * 32 + ((ks * 16 + q * 4) ^ ((rw & 7) << 2))];
        bias[nt2] = b1[rw];
    }
    float ps[2] = {0, 0}, ps2[2] = {0, 0};
#pragma unroll 1
    for (int mt = 0; mt < 8; ++mt) {
        int ar = mt * 16 + lr;
        bf16x8 a0 = *(const bf16x8*)&sY[ar * 32 + ((q * 4) ^ ((ar & 7) << 2))];
        bf16x8 a1 = *(const bf16x8*)&sY[ar * 32 + ((16 + q * 4) ^ ((ar & 7) << 2))];
#pragma unroll
        for (int nt2 = 0; nt2 < 2; ++nt2) {
            f32x4 acc;
            acc[0] = bias[nt2]; acc[1] = bias[nt2]; acc[2] = bias[nt2]; acc[3] = bias[nt2];
            acc = __builtin_amdgcn_mfma_f32_16x16x32_bf16(a0, bf[nt2][0], acc, 0, 0, 0);
            acc = __builtin_amdgcn_mfma_f32_16x16x32_bf16(a1, bf[nt2][1], acc, 0, 0, 0);
            int col = wv * 32 + nt2 * 16 + lr;
#pragma unroll
            for (int i = 0; i < 4; ++i) {
                long row = base + mt * 16 + q * 4 + i;
                float v = acc[i];
                unsigned hv = f2bf(v);
                unsigned ov = (unsigned)__shfl_xor((int)hv, 1, 64);
                bool in = row < (long)n;
                if (in) { ps[nt2] += v; ps2[nt2] += v * v; }
                if (in && (lr & 1) == 0)
                    h1b[row * 64 + ((unsigned)col >> 1)] = hv | (ov << 16);
            }
        }
    }
#pragma unroll
    for (int nt2 = 0; nt2 < 2; ++nt2) {
        float s = ps[nt2], s2 = ps2[nt2];
        s += __shfl_down(s, 32, 64);  s += __shfl_down(s, 16, 64);
        s2 += __shfl_down(s2, 32, 64); s2 += __shfl_down(s2, 16, 64);
        if (lane < 16) {
            int col = wv * 32 + nt2 * 16 + lr;
            part[(long)blockIdx.x * 256 + col] = s;
            part[(long)blockIdx.x * 256 + 128 + col] = s2;
        }
    }
}

// ---------------- BN reduce ----------------

__global__ __launch_bounds__(256) void k_bnred(const float* __restrict__ part,
                                               float* __restrict__ part2, int nblk) {
    int c = threadIdx.x;
    int b = blockIdx.x;
    float s = 0.f;
    for (int r = b; r < nblk; r += 64) s += part[(long)r * 256 + c];
    part2[b * 256 + c] = s;
}

__global__ __launch_bounds__(1024) void k_bnfin(const float* __restrict__ part2,
                        const float* __restrict__ gamma, const float* __restrict__ beta,
                        float* __restrict__ scale, float* __restrict__ shift, float invN) {
    __shared__ float red[4][256];
    __shared__ float tot[256];
    int c = threadIdx.x & 255;
    int g = threadIdx.x >> 8;
    float s = 0.f;
#pragma unroll
    for (int r = 0; r < 16; ++r) s += part2[(g * 16 + r) * 256 + c];
    red[g][c] = s;
    __syncthreads();
    if (threadIdx.x < 256) tot[c] = red[0][c] + red[1][c] + red[2][c] + red[3][c];
    __syncthreads();
    if (threadIdx.x < 128) {
        int cc = threadIdx.x;
        float mu = tot[cc] * invN;
        float var = fmaxf(tot[128 + cc] * invN - mu * mu, 0.f);
        float sc = gamma[cc] * rsqrtf(var + 1e-5f);
        scale[cc] = sc;
        shift[cc] = beta[cc] - mu * sc;
    }
}

// ---------------- GEMM2 (MFMA): relu(bn(h1b)) @ W2tb -> hout f32 (+ hb bf16) ----------

__global__ __launch_bounds__(256) void k_gemm2(const unsigned* __restrict__ h1b,
        const float* __restrict__ scale, const float* __restrict__ shift,
        const unsigned* __restrict__ W2tbL, const float* __restrict__ b2,
        float* __restrict__ hout, unsigned short* __restrict__ hb, int n, int dorelu) {
    __shared__ unsigned sA[128 * 64];
    __shared__ unsigned sW[64 * 64];
    __shared__ float sSc[128], sSh[128];
    int tid = threadIdx.x;
    int base = blockIdx.x * 128;
    if (tid < 128) { sSc[tid] = scale[tid]; sSh[tid] = shift[tid]; }
    for (int i = tid; i < 4096; i += 256) {
        int rw = i >> 6, cp = i & 63;
        sW[rw * 64 + (cp ^ ((rw & 7) << 2))] = W2tbL[i];
    }
    __syncthreads();
#pragma unroll
    for (int j = 0; j < 32; ++j) {
        int u = j * 256 + tid;
        int r = u >> 6, cp = u & 63;
        long row = base + r;
        unsigned w = 0;
        if (row < (long)n) {
            unsigned hv = h1b[row * 64 + cp];
            float v0 = fmaxf(bfu(hv & 0xffff) * sSc[2 * cp] + sSh[2 * cp], 0.f);
            float v1 = fmaxf(bfu(hv >> 16) * sSc[2 * cp + 1] + sSh[2 * cp + 1], 0.f);
            w = f2bf(v0) | (f2bf(v1) << 16);
        }
        sA[r * 64 + (cp ^ ((r & 7) << 2))] = w;
    }
    __syncthreads();
    int wv = tid >> 6, lane = tid & 63, lr = lane & 15, q = lane >> 4;
    bf16x8 bf[4];
    {
        int rw = wv * 16 + lr;
#pragma unroll
        for (int ks = 0; ks < 4; ++ks)
            bf[ks] = *(const bf16x8*)&sW[rw * 64 + ((ks * 16 + q * 4) ^ ((rw & 7) << 2))];
    }
    float bias = b2[wv * 16 + lr];
#pragma unroll 1
    for (int mt = 0; mt < 8; ++mt) {
        int ar = mt * 16 + lr;
        f32x4 acc;
        acc[0] = bias; acc[1] = bias; acc[2] = bias; acc[3] = bias;
#pragma unroll
        for (int ks = 0; ks < 4; ++ks) {
            bf16x8 a = *(const bf16x8*)&sA[ar * 64 + ((ks * 16 + q * 4) ^ ((ar & 7) << 2))];
            acc = __builtin_amdgcn_mfma_f32_16x16x32_bf16(a, bf[ks], acc, 0, 0, 0);
        }
        int col = wv * 16 + lr;
#pragma unroll
        for (int i = 0; i < 4; ++i) {
            long row = base + mt * 16 + q * 4 + i;
            float v = dorelu ? fmaxf(acc[i], 0.f) : acc[i];
            unsigned hv = f2bf(v);
            unsigned ov = (unsigned)__shfl_xor((int)hv, 1, 64);
            if (row < (long)n) {
                hout[row * 64 + col] = v;
                if (dorelu && (lr & 1) == 0)
                    *(unsigned*)(hb + row * 64 + (col & ~1)) = hv | (ov << 16);
            }
        }
    }
}

// ---------------- Head ----------------

__global__ __launch_bounds__(64) void k_head(const float* __restrict__ h,
        const int* __restrict__ gptr,
        const float* __restrict__ W1, const float* __restrict__ b1,
        const float* __restrict__ W2, const float* __restrict__ b2,
        float* __restrict__ out) {
    int g = blockIdx.x;
    int lane = threadIdx.x;
    int beg = gptr[g], end = gptr[g + 1];
    float s = 0.f;
    for (int r = beg; r < end; ++r) s += h[(long)r * 64 + lane];
    __shared__ float sg[64];
    sg[lane] = s;
    __syncthreads();
    float acc = b1[lane];
    for (int k = 0; k < 64; k++) acc += sg[k] * W1[k * 64 + lane];
    acc = fmaxf(acc, 0.f);
    float v = acc * W2[lane];
#pragma unroll
    for (int off = 32; off > 0; off >>= 1) v += __shfl_down(v, off, 64);
    if (lane == 0) out[g] = v + b2[0];
}

// ---------------- launch ----------------

extern "C" void kernel_launch(void* const* d_in, const int* in_sizes, int n_in,
                              void* d_out, int out_size, void* d_ws, size_t ws_size,
                              hipStream_t stream) {
    const float* x      = (const float*)d_in[0];
    const float* ea     = (const float*)d_in[1];
    const int*   ei     = (const int*)d_in[2];
    const int*   batch  = (const int*)d_in[3];
    const float* atomW1 = (const float*)d_in[4];
    const float* atomb1 = (const float*)d_in[5];
    const float* atomW2 = (const float*)d_in[6];
    const float* atomb2 = (const float*)d_in[7];
    const float* bondW1 = (const float*)d_in[8];
    const float* bondb1 = (const float*)d_in[9];
    const float* bondW2 = (const float*)d_in[10];
    const float* bondb2 = (const float*)d_in[11];
    const float* convT  = (const float*)d_in[12];
    const float* convW1 = (const float*)d_in[13];
    const float* convb1 = (const float*)d_in[14];
    const float* convG  = (const float*)d_in[15];
    const float* convBt = (const float*)d_in[16];
    const float* convW2 = (const float*)d_in[17];
    const float* convb2 = (const float*)d_in[18];
    const float* lin1W  = (const float*)d_in[19];
    const float* lin1b  = (const float*)d_in[20];
    const float* lin2W  = (const float*)d_in[21];
    const float* lin2b  = (const float*)d_in[22];
    float* out = (float*)d_out;

    const int N = in_sizes[0] / 32;
    const int E = in_sizes[1] / 16;
    const int G = out_size;
    const int Lconv = in_sizes[12];
    const int nchunk = (N + 1023) / 1024;
    const int nblk128 = (N + 127) / 128;
    const int NS64 = (N + 63) / 64;
    const int nchE2 = (E + ECH2 - 1) / ECH2;
    const size_t nquad = (size_t)((E + 3) / 4);

    size_t need = 0;
    auto count = [&](size_t bytes) { need += (bytes + 255) & ~(size_t)255; };
    count(nquad * 4 * 64 * 2);            // e_q
    count((size_t)N * 64 * 4);            // h_cur
    count((size_t)N * 64 * 2);            // h_bf
    count((size_t)N * 64 * 2);            // y_bf
    count((size_t)N * 128 * 2);           // h1b
    count((size_t)E * 8);                 // spe
    count((size_t)E * 8);                 // staging
    count((size_t)(N + 1) * 4);
    count((size_t)N * 4);                 // counts
    count((size_t)N * 4);                 // fill
    count(256);                           // bfill
    count((size_t)(G + 1) * 4);
    count((size_t)nblk128 * 256 * 4);     // part
    count((size_t)64 * 256 * 4);          // part2
    count(128 * 4); count(128 * 4);
    count((size_t)(nchunk + 1) * 4);
    count(4);
    count(1024 * 2);
    count(4096 * 2);
    count((size_t)Lconv * 8192 * 2);
    count((size_t)Lconv * 8192 * 2);
    if (ws_size < need) {
        hipMemsetAsync(d_out, 0, (size_t)out_size * 4, stream);
        return;
    }

    char* ws = (char*)d_ws;
    size_t off = 0;
    auto alloc = [&](size_t bytes) -> void* {
        void* p = ws + off;
        off += (bytes + 255) & ~(size_t)255;
        return p;
    };
    unsigned short* e_q = (unsigned short*)alloc(nquad * 4 * 64 * 2);
    float* h_cur    = (float*)alloc((size_t)N * 64 * 4);
    unsigned short* h_bf = (unsigned short*)alloc((size_t)N * 64 * 2);
    unsigned short* y_bf = (unsigned short*)alloc((size_t)N * 64 * 2);
    unsigned short* h1b  = (unsigned short*)alloc((size_t)N * 128 * 2);
    int2*  spe      = (int2*)alloc((size_t)E * 8);
    unsigned long long* staging = (unsigned long long*)alloc((size_t)E * 8);
    int*   row_ptr  = (int*)alloc((size_t)(N + 1) * 4);
    int*   counts   = (int*)alloc((size_t)N * 4);
    int*   fill     = (int*)alloc((size_t)N * 4);
    int*   bfill    = (int*)alloc(256);
    int*   gptr     = (int*)alloc((size_t)(G + 1) * 4);
    float* part     = (float*)alloc((size_t)nblk128 * 256 * 4);
    float* part2    = (float*)alloc((size_t)64 * 256 * 4);
    float* bnscale  = (float*)alloc(128 * 4);
    float* bnshift  = (float*)alloc(128 * 4);
    int*   csum     = (int*)alloc((size_t)(nchunk + 1) * 4);
    int*   totalp   = (int*)alloc(4);
    unsigned short* W1b  = (unsigned short*)alloc(1024 * 2);
    unsigned short* W2tb = (unsigned short*)alloc(4096 * 2);
    unsigned short* cW1tb = (unsigned short*)alloc((size_t)Lconv * 8192 * 2);
    unsigned short* cW2tb = (unsigned short*)alloc((size_t)Lconv * 8192 * 2);
    (void)n_in;

    hipMemsetAsync(counts, 0, (size_t)N * 4, stream);
    hipMemsetAsync(fill, 0, (size_t)N * 4, stream);
    hipMemsetAsync(bfill, 0, 256, stream);

    const int* src = ei;
    const int* dst = ei + E;

    k_hist<<<(E + 255) / 256, 256, 0, stream>>>(dst, counts, E);
    k_scan1<<<nchunk, 1024, 0, stream>>>(counts, row_ptr, csum, N);
    k_scan2<<<1, 64, 0, stream>>>(csum, nchunk, totalp);
    k_scan3<<<(N + 255) / 256, 256, 0, stream>>>(row_ptr, csum, totalp, N);
    k_part<<<nchE2, 256, 0, stream>>>(src, dst, row_ptr, bfill, staging, E, NS64, N);
    k_scat2<<<128, 256, 0, stream>>>(staging, row_ptr, fill, spe, NS64, N);
    k_gptr<<<(N + 256) / 256, 256, 0, stream>>>(batch, gptr, N, G);
    k_wt<<<16, 256, 0, stream>>>(bondW1, bondW2, W1b, W2tb);
    k_wtc<<<(Lconv * 8192 + 255) / 256, 256, 0, stream>>>(convW1, convW2, cW1tb, cW2tb, Lconv);

    k_atom<<<(N + TM - 1) / TM, 256, 0, stream>>>(x, atomW1, atomb1, atomW2, atomb2,
                                                  h_cur, h_bf, N);
    k_bond<<<(E + 127) / 128, 256, 0, stream>>>(ea, spe, W1b, bondb1, W2tb, bondb2, e_q, E);

    for (int l = 0; l < Lconv; ++l) {
        k_agg<<<(N + 3) / 4, 256, 0, stream>>>(h_cur, h_bf, e_q, spe, row_ptr, convT, l,
                                               y_bf, N);
        k_gemm1<<<nblk128, 256, 0, stream>>>((const unsigned*)y_bf,
                                             (const unsigned*)(cW1tb + (size_t)l * 8192),
                                             convb1 + (size_t)l * 128,
                                             (unsigned*)h1b, part, N);
        k_bnred<<<64, 256, 0, stream>>>(part, part2, nblk128);
        k_bnfin<<<1, 1024, 0, stream>>>(part2, convG + (size_t)l * 128, convBt + (size_t)l * 128,
                                        bnscale, bnshift, 1.0f / (float)N);
        k_gemm2<<<nblk128, 256, 0, stream>>>((const unsigned*)h1b, bnscale, bnshift,
                                             (const unsigned*)(cW2tb + (size_t)l * 8192),
                                             convb2 + (size_t)l * 64, h_cur, h_bf, N,
                                             (l < Lconv - 1) ? 1 : 0);
    }

    k_head<<<G, 64, 0, stream>>>(h_cur, gptr, lin1W, lin1b, lin2W, lin2b, out);
}

// Round 16
// 527.524 us; speedup vs baseline: 1.0177x; 1.0177x over previous
//
#include <hip/hip_runtime.h>
#include <hip/hip_bf16.h>
#include <math.h>

typedef __attribute__((ext_vector_type(8))) short bf16x8;
typedef __attribute__((ext_vector_type(4))) float f32x4;

__device__ inline unsigned f2bf(float f) {
    union { __hip_bfloat16 h; unsigned short u; } cv;
    cv.h = __float2bfloat16(f);
    return (unsigned)cv.u;
}
__device__ inline float bfu(unsigned u) {          // bf16 bits -> float
    return __uint_as_float(u << 16);
}

// ---------------- CSR construction ----------------

__global__ void k_hist(const int* __restrict__ dst, int* __restrict__ counts, int E) {
    int e = blockIdx.x * blockDim.x + threadIdx.x;
    if (e < E) atomicAdd(&counts[dst[e]], 1);
}

__global__ void k_scan1(const int* __restrict__ counts, int* __restrict__ row_ptr,
                        int* __restrict__ csum, int n) {
    __shared__ int buf[1024];
    int tid = threadIdx.x;
    int base = blockIdx.x * 1024;
    int v = (base + tid < n) ? counts[base + tid] : 0;
    buf[tid] = v;
    __syncthreads();
    int inc = v;
    for (int off = 1; off < 1024; off <<= 1) {
        int add = (tid >= off) ? buf[tid - off] : 0;
        __syncthreads();
        inc += add;
        buf[tid] = inc;
        __syncthreads();
    }
    if (base + tid < n) row_ptr[base + tid] = inc - v;
    if (tid == 1023) csum[blockIdx.x] = inc;
}

__global__ void k_scan2(int* __restrict__ csum, int nc, int* __restrict__ total) {
    if (threadIdx.x == 0) {
        int run = 0;
        for (int i = 0; i < nc; ++i) { int c = csum[i]; csum[i] = run; run += c; }
        *total = run;
    }
}

__global__ void k_scan3(int* __restrict__ row_ptr, const int* __restrict__ csum,
                        const int* __restrict__ total, int n) {
    int i = blockIdx.x * blockDim.x + threadIdx.x;
    if (i < n) row_ptr[i] += csum[i >> 10];
    if (i == 0) row_ptr[n] = *total;
}

// ---------------- Two-phase bucketed scatter ----------------

#define ECH2 4096
__global__ __launch_bounds__(256) void k_part(const int* __restrict__ src,
        const int* __restrict__ dst, const int* __restrict__ row_ptr,
        int* __restrict__ bfill, unsigned long long* __restrict__ staging,
        int E, int NS64, int N) {
    __shared__ int lh[64], lbase[64], lfill[64];
    int tid = threadIdx.x;
    if (tid < 64) lh[tid] = 0;
    __syncthreads();
    int base = blockIdx.x * ECH2;
#pragma unroll 1
    for (int j = 0; j < ECH2 / 256; ++j) {
        int e = base + j * 256 + tid;
        if (e < E) atomicAdd(&lh[dst[e] / NS64], 1);
    }
    __syncthreads();
    if (tid < 64) {
        int bs = row_ptr[min(tid * NS64, N)];
        lbase[tid] = bs + atomicAdd(&bfill[tid], lh[tid]);
        lfill[tid] = 0;
    }
    __syncthreads();
#pragma unroll 1
    for (int j = 0; j < ECH2 / 256; ++j) {
        int e = base + j * 256 + tid;
        if (e < E) {
            int d = dst[e];
            int b = d / NS64;
            int r = atomicAdd(&lfill[b], 1);
            unsigned long long pk = (unsigned long long)((unsigned)src[e] & 0xffffffu)
                | ((unsigned long long)((unsigned)(d - b * NS64) & 0xffffu) << 24)
                | ((unsigned long long)(unsigned)e << 40);
            staging[lbase[b] + r] = pk;
        }
    }
}

__global__ __launch_bounds__(256) void k_scat2(const unsigned long long* __restrict__ staging,
        const int* __restrict__ row_ptr, int* __restrict__ fill,
        int2* __restrict__ spe, int NS64, int N) {
    int b = blockIdx.x >> 1;
    int half = blockIdx.x & 1;
    int s0 = row_ptr[min(b * NS64, N)];
    int s1 = row_ptr[min((b + 1) * NS64, N)];
    int cnt = s1 - s0;
    int h0 = cnt >> 1;
    int start = s0 + (half ? h0 : 0);
    int len = half ? (cnt - h0) : h0;
    for (int i = threadIdx.x; i < len; i += 256) {
        unsigned long long pk = staging[start + i];
        int srcv = (int)(pk & 0xffffffu);
        int dloc = (int)((pk >> 24) & 0xffffu);
        int eid  = (int)(pk >> 40);
        int d = b * NS64 + dloc;
        int pos = row_ptr[d] + atomicAdd(&fill[d], 1);
        spe[pos] = make_int2(srcv, eid);
    }
}

__global__ void k_gptr(const int* __restrict__ batch, int* __restrict__ gptr, int n, int G) {
    int i = blockIdx.x * blockDim.x + threadIdx.x;
    if (i > n) return;
    if (i == 0) {
        int b0 = batch[0];
        for (int g = 0; g <= b0; ++g) gptr[g] = 0;
    } else if (i == n) {
        int bl = batch[n - 1];
        for (int g = bl + 1; g <= G; ++g) gptr[g] = n;
    } else {
        int b = batch[i], pb = batch[i - 1];
        for (int g = pb + 1; g <= b; ++g) gptr[g] = i;
    }
}

// ---------------- weight prep ----------------

__global__ void k_wt(const float* __restrict__ W1, const float* __restrict__ W2,
                     unsigned short* __restrict__ W1b, unsigned short* __restrict__ W2tb) {
    int tid = blockIdx.x * blockDim.x + threadIdx.x;
    if (tid < 1024) {
        int j = tid / 16, k = tid % 16;
        W1b[j * 16 + k] = (unsigned short)f2bf(W1[k * 64 + j]);
    }
    if (tid < 4096) {
        int j = tid / 64, k = tid % 64;
        W2tb[j * 64 + k] = (unsigned short)f2bf(W2[k * 64 + j]);
    }
}

__global__ void k_wtc(const float* __restrict__ W1, const float* __restrict__ W2,
                      unsigned short* __restrict__ W1tb, unsigned short* __restrict__ W2tb,
                      int L) {
    int idx = blockIdx.x * blockDim.x + threadIdx.x;
    int tot = L * 8192;
    if (idx < tot) {
        int l = idx / 8192, r = idx % 8192;
        int j = r / 64, k = r % 64;
        W1tb[(long)l * 8192 + j * 64 + k] = (unsigned short)f2bf(W1[(long)l * 8192 + k * 128 + j]);
        int j2 = r / 128, k2 = r % 128;
        W2tb[(long)l * 8192 + j2 * 128 + k2] =
            (unsigned short)f2bf(W2[(long)l * 8192 + k2 * 64 + j2]);
    }
}

// ---------------- Atom encoder: [M,32] -> relu -> [M,64] -> relu -> h_bf (bf16 only) ----

#define TM 128
__global__ __launch_bounds__(256) void k_atom(const float* __restrict__ x,
        const float* __restrict__ W1, const float* __restrict__ b1,
        const float* __restrict__ W2, const float* __restrict__ b2,
        unsigned short* __restrict__ hb, int M) {
    __shared__ float sU[TM * 65];
    __shared__ float sW1[32 * 64];
    __shared__ float sW2[64 * 64];
    __shared__ float sB1[64], sB2[64];
#define A_IN(r, c) sU[(r) * 33 + (c)]
#define A_T1(r, c) sU[(r) * 65 + (c)]
    int tid = threadIdx.x;
    int base = blockIdx.x * TM;
    for (int i = tid; i < 32 * 64 / 4; i += 256) ((float4*)sW1)[i] = ((const float4*)W1)[i];
    for (int i = tid; i < 64 * 64 / 4; i += 256) ((float4*)sW2)[i] = ((const float4*)W2)[i];
    if (tid < 64) { sB1[tid] = b1[tid]; sB2[tid] = b2[tid]; }
    for (int i = tid; i < TM * 32 / 4; i += 256) {
        int r = i / 8, c4 = i % 8;
        int row = base + r;
        float4 v = (row < M) ? ((const float4*)(x + (long)row * 32))[c4] : make_float4(0, 0, 0, 0);
        A_IN(r, c4 * 4 + 0) = v.x; A_IN(r, c4 * 4 + 1) = v.y;
        A_IN(r, c4 * 4 + 2) = v.z; A_IN(r, c4 * 4 + 3) = v.w;
    }
    __syncthreads();
    int r0 = (tid / 16) * 8;
    int c0 = (tid % 16) * 4;
    float acc[8][4];
#pragma unroll
    for (int i = 0; i < 8; i++)
#pragma unroll
        for (int j = 0; j < 4; j++) acc[i][j] = sB1[c0 + j];
    for (int k = 0; k < 32; k++) {
        float a[8], b[4];
#pragma unroll
        for (int i = 0; i < 8; i++) a[i] = A_IN(r0 + i, k);
#pragma unroll
        for (int j = 0; j < 4; j++) b[j] = sW1[k * 64 + c0 + j];
#pragma unroll
        for (int i = 0; i < 8; i++)
#pragma unroll
            for (int j = 0; j < 4; j++) acc[i][j] += a[i] * b[j];
    }
    __syncthreads();
#pragma unroll
    for (int i = 0; i < 8; i++)
#pragma unroll
        for (int j = 0; j < 4; j++) A_T1(r0 + i, c0 + j) = fmaxf(acc[i][j], 0.f);
    __syncthreads();
#pragma unroll
    for (int i = 0; i < 8; i++)
#pragma unroll
        for (int j = 0; j < 4; j++) acc[i][j] = sB2[c0 + j];
    for (int k = 0; k < 64; k++) {
        float a[8], b[4];
#pragma unroll
        for (int i = 0; i < 8; i++) a[i] = A_T1(r0 + i, k);
#pragma unroll
        for (int j = 0; j < 4; j++) b[j] = sW2[k * 64 + c0 + j];
#pragma unroll
        for (int i = 0; i < 8; i++)
#pragma unroll
            for (int j = 0; j < 4; j++) acc[i][j] += a[i] * b[j];
    }
#pragma unroll
    for (int i = 0; i < 8; i++) {
        int row = base + r0 + i;
        if (row < M) {
            unsigned p01 = f2bf(fmaxf(acc[i][0], 0.f)) | (f2bf(fmaxf(acc[i][1], 0.f)) << 16);
            unsigned p23 = f2bf(fmaxf(acc[i][2], 0.f)) | (f2bf(fmaxf(acc[i][3], 0.f)) << 16);
            *(uint2*)(hb + (long)row * 64 + c0) = make_uint2(p01, p23);
        }
    }
}

// ---------------- Bond encoder: BOTH layers via MFMA; layer1 swapped (D=[ch][edge]) ----

__global__ __launch_bounds__(256) void k_bond(const float* __restrict__ ea,
        const int2* __restrict__ spe,
        const unsigned short* __restrict__ W1b, const float* __restrict__ b1,
        const unsigned short* __restrict__ W2tb, const float* __restrict__ b2,
        unsigned short* __restrict__ e_q, int E) {
    __shared__ unsigned sT1[128 * 32];
    __shared__ unsigned sW2[64 * 32];
    int tid = threadIdx.x;

    for (int i = tid; i < 2048; i += 256) {
        int rw = i >> 5, cp = i & 31;
        sW2[rw * 32 + (cp ^ ((rw & 7) << 2))] = ((const unsigned*)W2tb)[i];
    }

    int wv = tid >> 6, lane = tid & 63;
    int lr = lane & 15, q = lane >> 4;

    union { bf16x8 v; uint4 u4; } bf1[4];
    float4 bias1[4];
#pragma unroll
    for (int nt = 0; nt < 4; ++nt) {
        bf1[nt].u4 = make_uint4(0, 0, 0, 0);
        if (q < 2)
            bf1[nt].u4 = *(const uint4*)(W1b + (nt * 16 + lr) * 16 + q * 8);
        bias1[nt] = *(const float4*)(b1 + nt * 16 + q * 4);
    }

#pragma unroll
    for (int mt1 = 0; mt1 < 2; ++mt1) {
        int rtile = wv * 2 + mt1;
        long row1 = (long)blockIdx.x * 128 + rtile * 16 + lr;
        long eidx = row1 < (long)E ? row1 : (long)(E - 1);
        int eid = spe[eidx].y;
        union { bf16x8 v; uint4 u4; unsigned u[4]; } af1;
        af1.u4 = make_uint4(0, 0, 0, 0);
        if (q < 2) {
            const float4* er = (const float4*)(ea + (long)eid * 16 + q * 8);
            float4 u0 = er[0], u1 = er[1];
            af1.u[0] = f2bf(u0.x) | (f2bf(u0.y) << 16);
            af1.u[1] = f2bf(u0.z) | (f2bf(u0.w) << 16);
            af1.u[2] = f2bf(u1.x) | (f2bf(u1.y) << 16);
            af1.u[3] = f2bf(u1.z) | (f2bf(u1.w) << 16);
        }
        int r = rtile * 16 + lr;
#pragma unroll
        for (int nt = 0; nt < 4; ++nt) {
            f32x4 c0;
            c0[0] = bias1[nt].x; c0[1] = bias1[nt].y;
            c0[2] = bias1[nt].z; c0[3] = bias1[nt].w;
            f32x4 d = __builtin_amdgcn_mfma_f32_16x16x32_bf16(bf1[nt].v, af1.v, c0, 0, 0, 0);
            unsigned p01 = f2bf(fmaxf(d[0], 0.f)) | (f2bf(fmaxf(d[1], 0.f)) << 16);
            unsigned p23 = f2bf(fmaxf(d[2], 0.f)) | (f2bf(fmaxf(d[3], 0.f)) << 16);
            int cp = nt * 8 + q * 2;
            sT1[r * 32 + (cp ^ ((r & 7) << 2))] = p01;
            sT1[r * 32 + ((cp + 1) ^ ((r & 7) << 2))] = p23;
        }
    }
    __syncthreads();

    bf16x8 bf[4][2];
#pragma unroll
    for (int nt = 0; nt < 4; ++nt)
#pragma unroll
        for (int ks = 0; ks < 2; ++ks) {
            int rw = nt * 16 + lr;
            int u = rw * 32 + ((ks * 16 + q * 4) ^ ((rw & 7) << 2));
            bf[nt][ks] = *(const bf16x8*)&sW2[u];
        }
    f32x4 acc[2][4];
#pragma unroll
    for (int mt = 0; mt < 2; ++mt)
#pragma unroll
        for (int nt = 0; nt < 4; ++nt) {
            float bias = b2[nt * 16 + lr];
            f32x4 c0; c0[0] = bias; c0[1] = bias; c0[2] = bias; c0[3] = bias;
            acc[mt][nt] = c0;
        }
#pragma unroll
    for (int mt = 0; mt < 2; ++mt) {
        int rw = (wv * 2 + mt) * 16 + lr;
#pragma unroll
        for (int ks = 0; ks < 2; ++ks) {
            int u = rw * 32 + ((ks * 16 + q * 4) ^ ((rw & 7) << 2));
            bf16x8 af = *(const bf16x8*)&sT1[u];
#pragma unroll
            for (int nt = 0; nt < 4; ++nt)
                acc[mt][nt] = __builtin_amdgcn_mfma_f32_16x16x32_bf16(
                    af, bf[nt][ks], acc[mt][nt], 0, 0, 0);
        }
    }
#pragma unroll
    for (int mt = 0; mt < 2; ++mt)
#pragma unroll
        for (int nt = 0; nt < 4; ++nt) {
            long r0 = (long)blockIdx.x * 128 + (wv * 2 + mt) * 16 + q * 4;
            unsigned p01 = f2bf(fmaxf(acc[mt][nt][0], 0.f)) |
                           (f2bf(fmaxf(acc[mt][nt][1], 0.f)) << 16);
            unsigned p23 = f2bf(fmaxf(acc[mt][nt][2], 0.f)) |
                           (f2bf(fmaxf(acc[mt][nt][3], 0.f)) << 16);
            long qb = ((r0 >> 2) * 64 + nt * 16 + lr) * 4;
            if (r0 + 3 < (long)E) {
                *(uint2*)(e_q + qb) = make_uint2(p01, p23);
            } else {
                unsigned vv[4] = {p01 & 0xffff, p01 >> 16, p23 & 0xffff, p23 >> 16};
#pragma unroll
                for (int i = 0; i < 4; ++i)
                    if (r0 + i < (long)E) e_q[qb + i] = (unsigned short)vv[i];
            }
        }
}

// ---------------- Aggregation: bf16 gathers + bf16 residual; 8-wide online softmax -----

__global__ __launch_bounds__(256) void k_agg(const unsigned short* __restrict__ h_bf,
        const unsigned short* __restrict__ e_q, const int2* __restrict__ spe,
        const int* __restrict__ row_ptr, const float* __restrict__ t_ptr, int layer,
        unsigned short* __restrict__ yb, int n) {
    int wid = blockIdx.x * 4 + (threadIdx.x >> 6);
    int lane = threadIdx.x & 63;
    if (wid >= n) return;
    wid = __builtin_amdgcn_readfirstlane(wid);
    float tval = t_ptr[layer];
    int beg = row_ptr[wid], end = row_ptr[wid + 1];
    float m = -INFINITY, den = 0.f, num = 0.f;
    int i = beg;
    int astart = (beg + 3) & ~3; if (astart > end) astart = end;
    int aend = end & ~3;         if (aend < astart) aend = astart;
    for (; i < astart; ++i) {
        int s = spe[i].x;
        float ev = bfu((unsigned)e_q[((long)(i >> 2) * 64 + lane) * 4 + (i & 3)]);
        float hv = bfu((unsigned)h_bf[(long)s * 64 + lane]);
        float msg = fmaxf(hv + ev, 0.f) + 1e-7f;
        float sv = msg * tval;
        float mn = fmaxf(m, sv);
        float sc = __expf(m - mn);
        float w = __expf(sv - mn);
        den = den * sc + w;
        num = num * sc + w * msg;
        m = mn;
    }
    for (; i + 8 <= aend; i += 8) {
        int s0 = spe[i].x,     s1 = spe[i + 1].x, s2 = spe[i + 2].x, s3 = spe[i + 3].x;
        int s4 = spe[i + 4].x, s5 = spe[i + 5].x, s6 = spe[i + 6].x, s7 = spe[i + 7].x;
        uint2 ea0 = *(const uint2*)(e_q + ((long)(i >> 2) * 64 + lane) * 4);
        uint2 ea1 = *(const uint2*)(e_q + ((long)((i >> 2) + 1) * 64 + lane) * 4);
        float hv0 = bfu((unsigned)h_bf[(long)s0 * 64 + lane]);
        float hv1 = bfu((unsigned)h_bf[(long)s1 * 64 + lane]);
        float hv2 = bfu((unsigned)h_bf[(long)s2 * 64 + lane]);
        float hv3 = bfu((unsigned)h_bf[(long)s3 * 64 + lane]);
        float hv4 = bfu((unsigned)h_bf[(long)s4 * 64 + lane]);
        float hv5 = bfu((unsigned)h_bf[(long)s5 * 64 + lane]);
        float hv6 = bfu((unsigned)h_bf[(long)s6 * 64 + lane]);
        float hv7 = bfu((unsigned)h_bf[(long)s7 * 64 + lane]);
        float msg0 = fmaxf(hv0 + bfu(ea0.x & 0xffff), 0.f) + 1e-7f;
        float msg1 = fmaxf(hv1 + bfu(ea0.x >> 16), 0.f) + 1e-7f;
        float msg2 = fmaxf(hv2 + bfu(ea0.y & 0xffff), 0.f) + 1e-7f;
        float msg3 = fmaxf(hv3 + bfu(ea0.y >> 16), 0.f) + 1e-7f;
        float msg4 = fmaxf(hv4 + bfu(ea1.x & 0xffff), 0.f) + 1e-7f;
        float msg5 = fmaxf(hv5 + bfu(ea1.x >> 16), 0.f) + 1e-7f;
        float msg6 = fmaxf(hv6 + bfu(ea1.y & 0xffff), 0.f) + 1e-7f;
        float msg7 = fmaxf(hv7 + bfu(ea1.y >> 16), 0.f) + 1e-7f;
        float sv0 = msg0 * tval, sv1 = msg1 * tval, sv2 = msg2 * tval, sv3 = msg3 * tval;
        float sv4 = msg4 * tval, sv5 = msg5 * tval, sv6 = msg6 * tval, sv7 = msg7 * tval;
        float mn = fmaxf(fmaxf(fmaxf(fmaxf(m, sv0), fmaxf(sv1, sv2)),
                               fmaxf(fmaxf(sv3, sv4), fmaxf(sv5, sv6))), sv7);
        float sc = __expf(m - mn);
        float w0 = __expf(sv0 - mn), w1 = __expf(sv1 - mn);
        float w2 = __expf(sv2 - mn), w3 = __expf(sv3 - mn);
        float w4 = __expf(sv4 - mn), w5 = __expf(sv5 - mn);
        float w6 = __expf(sv6 - mn), w7 = __expf(sv7 - mn);
        den = den * sc + (((w0 + w1) + (w2 + w3)) + ((w4 + w5) + (w6 + w7)));
        num = num * sc + (((w0 * msg0 + w1 * msg1) + (w2 * msg2 + w3 * msg3)) +
                          ((w4 * msg4 + w5 * msg5) + (w6 * msg6 + w7 * msg7)));
        m = mn;
    }
    for (; i < aend; i += 4) {
        int s0 = spe[i].x, s1 = spe[i + 1].x, s2 = spe[i + 2].x, s3 = spe[i + 3].x;
        uint2 ee = *(const uint2*)(e_q + ((long)(i >> 2) * 64 + lane) * 4);
        float hv0 = bfu((unsigned)h_bf[(long)s0 * 64 + lane]);
        float hv1 = bfu((unsigned)h_bf[(long)s1 * 64 + lane]);
        float hv2 = bfu((unsigned)h_bf[(long)s2 * 64 + lane]);
        float hv3 = bfu((unsigned)h_bf[(long)s3 * 64 + lane]);
        float msg0 = fmaxf(hv0 + bfu(ee.x & 0xffff), 0.f) + 1e-7f;
        float msg1 = fmaxf(hv1 + bfu(ee.x >> 16), 0.f) + 1e-7f;
        float msg2 = fmaxf(hv2 + bfu(ee.y & 0xffff), 0.f) + 1e-7f;
        float msg3 = fmaxf(hv3 + bfu(ee.y >> 16), 0.f) + 1e-7f;
        float sv0 = msg0 * tval, sv1 = msg1 * tval;
        float sv2 = msg2 * tval, sv3 = msg3 * tval;
        float mn = fmaxf(fmaxf(fmaxf(m, sv0), fmaxf(sv1, sv2)), sv3);
        float sc = __expf(m - mn);
        float w0 = __expf(sv0 - mn);
        float w1 = __expf(sv1 - mn);
        float w2 = __expf(sv2 - mn);
        float w3 = __expf(sv3 - mn);
        den = den * sc + ((w0 + w1) + (w2 + w3));
        num = num * sc + ((w0 * msg0 + w1 * msg1) + (w2 * msg2 + w3 * msg3));
        m = mn;
    }
    for (; i < end; ++i) {
        int s = spe[i].x;
        float ev = bfu((unsigned)e_q[((long)(i >> 2) * 64 + lane) * 4 + (i & 3)]);
        float hv = bfu((unsigned)h_bf[(long)s * 64 + lane]);
        float msg = fmaxf(hv + ev, 0.f) + 1e-7f;
        float sv = msg * tval;
        float mn = fmaxf(m, sv);
        float sc = __expf(m - mn);
        float w = __expf(sv - mn);
        den = den * sc + w;
        num = num * sc + w * msg;
        m = mn;
    }
    float agg = (end > beg) ? num / (den + 1e-16f) : 0.f;
    float hres = bfu((unsigned)h_bf[(long)wid * 64 + lane]);
    yb[(long)wid * 64 + lane] = (unsigned short)f2bf(hres + agg);
}

// ---------------- GEMM1 (MFMA): yb[N,64]bf16 @ W1tb -> h1b[N,128]bf16 + BN partials ----

__global__ __launch_bounds__(256) void k_gemm1(const unsigned* __restrict__ yb,
        const unsigned* __restrict__ W1tb, const float* __restrict__ b1,
        unsigned* __restrict__ h1b, float* __restrict__ part, int n) {
    __shared__ unsigned sY[128 * 32];
    __shared__ unsigned sW[128 * 32];
    int tid = threadIdx.x;
    int base = blockIdx.x * 128;
    for (int i = tid; i < 4096; i += 256) {
        int rw = i >> 5, cp = i & 31;
        sW[rw * 32 + (cp ^ ((rw & 7) << 2))] = W1tb[i];
    }
#pragma unroll
    for (int j = 0; j < 16; ++j) {
        int u = j * 256 + tid;
        int r = u >> 5, cp = u & 31;
        long row = base + r;
        unsigned v = (row < (long)n) ? yb[row * 32 + cp] : 0u;
        sY[r * 32 + (cp ^ ((r & 7) << 2))] = v;
    }
    __syncthreads();
    int wv = tid >> 6, lane = tid & 63, lr = lane & 15, q = lane >> 4;
    bf16x8 bf[2][2];
    float bias[2];
#pragma unroll
    for (int nt2 = 0; nt2 < 2; ++nt2) {
        int rw = wv * 32 + nt2 * 16 + lr;
#pragma unroll
        for (int ks = 0; ks < 2; ++ks)
            bf[nt2][ks] = *(const bf16x8*)&sW[rw * 32 + ((ks * 16 + q * 4) ^ ((rw & 7) << 2))];
        bias[nt2] = b1[rw];
    }
    float ps[2] = {0, 0}, ps2[2] = {0, 0};
#pragma unroll 1
    for (int mt = 0; mt < 8; ++mt) {
        int ar = mt * 16 + lr;
        bf16x8 a0 = *(const bf16x8*)&sY[ar * 32 + ((q * 4) ^ ((ar & 7) << 2))];
        bf16x8 a1 = *(const bf16x8*)&sY[ar * 32 + ((16 + q * 4) ^ ((ar & 7) << 2))];
#pragma unroll
        for (int nt2 = 0; nt2 < 2; ++nt2) {
            f32x4 acc;
            acc[0] = bias[nt2]; acc[1] = bias[nt2]; acc[2] = bias[nt2]; acc[3] = bias[nt2];
            acc = __builtin_amdgcn_mfma_f32_16x16x32_bf16(a0, bf[nt2][0], acc, 0, 0, 0);
            acc = __builtin_amdgcn_mfma_f32_16x16x32_bf16(a1, bf[nt2][1], acc, 0, 0, 0);
            int col = wv * 32 + nt2 * 16 + lr;
#pragma unroll
            for (int i = 0; i < 4; ++i) {
                long row = base + mt * 16 + q * 4 + i;
                float v = acc[i];
                unsigned hv = f2bf(v);
                unsigned ov = (unsigned)__shfl_xor((int)hv, 1, 64);
                bool in = row < (long)n;
                if (in) { ps[nt2] += v; ps2[nt2] += v * v; }
                if (in && (lr & 1) == 0)
                    h1b[row * 64 + ((unsigned)col >> 1)] = hv | (ov << 16);
            }
        }
    }
#pragma unroll
    for (int nt2 = 0; nt2 < 2; ++nt2) {
        float s = ps[nt2], s2 = ps2[nt2];
        s += __shfl_down(s, 32, 64);  s += __shfl_down(s, 16, 64);
        s2 += __shfl_down(s2, 32, 64); s2 += __shfl_down(s2, 16, 64);
        if (lane < 16) {
            int col = wv * 32 + nt2 * 16 + lr;
            part[(long)blockIdx.x * 256 + col] = s;
            part[(long)blockIdx.x * 256 + 128 + col] = s2;
        }
    }
}

// ---------------- BN reduce ----------------

__global__ __launch_bounds__(256) void k_bnred(const float* __restrict__ part,
                                               float* __restrict__ part2, int nblk) {
    int c = threadIdx.x;
    int b = blockIdx.x;
    float s = 0.f;
    for (int r = b; r < nblk; r += 64) s += part[(long)r * 256 + c];
    part2[b * 256 + c] = s;
}

__global__ __launch_bounds__(1024) void k_bnfin(const float* __restrict__ part2,
                        const float* __restrict__ gamma, const float* __restrict__ beta,
                        float* __restrict__ scale, float* __restrict__ shift, float invN) {
    __shared__ float red[4][256];
    __shared__ float tot[256];
    int c = threadIdx.x & 255;
    int g = threadIdx.x >> 8;
    float s = 0.f;
#pragma unroll
    for (int r = 0; r < 16; ++r) s += part2[(g * 16 + r) * 256 + c];
    red[g][c] = s;
    __syncthreads();
    if (threadIdx.x < 256) tot[c] = red[0][c] + red[1][c] + red[2][c] + red[3][c];
    __syncthreads();
    if (threadIdx.x < 128) {
        int cc = threadIdx.x;
        float mu = tot[cc] * invN;
        float var = fmaxf(tot[128 + cc] * invN - mu * mu, 0.f);
        float sc = gamma[cc] * rsqrtf(var + 1e-5f);
        scale[cc] = sc;
        shift[cc] = beta[cc] - mu * sc;
    }
}

// ---------------- GEMM2 (MFMA): relu(bn(h1b)) @ W2tb -> hb bf16 (mid) / hout f32 (last) --

__global__ __launch_bounds__(256) void k_gemm2(const unsigned* __restrict__ h1b,
        const float* __restrict__ scale, const float* __restrict__ shift,
        const unsigned* __restrict__ W2tbL, const float* __restrict__ b2,
        float* __restrict__ hout, unsigned short* __restrict__ hb, int n, int dorelu) {
    __shared__ unsigned sA[128 * 64];
    __shared__ unsigned sW[64 * 64];
    __shared__ float sSc[128], sSh[128];
    int tid = threadIdx.x;
    int base = blockIdx.x * 128;
    if (tid < 128) { sSc[tid] = scale[tid]; sSh[tid] = shift[tid]; }
    for (int i = tid; i < 4096; i += 256) {
        int rw = i >> 6, cp = i & 63;
        sW[rw * 64 + (cp ^ ((rw & 7) << 2))] = W2tbL[i];
    }
    __syncthreads();
#pragma unroll
    for (int j = 0; j < 32; ++j) {
        int u = j * 256 + tid;
        int r = u >> 6, cp = u & 63;
        long row = base + r;
        unsigned w = 0;
        if (row < (long)n) {
            unsigned hv = h1b[row * 64 + cp];
            float v0 = fmaxf(bfu(hv & 0xffff) * sSc[2 * cp] + sSh[2 * cp], 0.f);
            float v1 = fmaxf(bfu(hv >> 16) * sSc[2 * cp + 1] + sSh[2 * cp + 1], 0.f);
            w = f2bf(v0) | (f2bf(v1) << 16);
        }
        sA[r * 64 + (cp ^ ((r & 7) << 2))] = w;
    }
    __syncthreads();
    int wv = tid >> 6, lane = tid & 63, lr = lane & 15, q = lane >> 4;
    bf16x8 bf[4];
    {
        int rw = wv * 16 + lr;
#pragma unroll
        for (int ks = 0; ks < 4; ++ks)
            bf[ks] = *(const bf16x8*)&sW[rw * 64 + ((ks * 16 + q * 4) ^ ((rw & 7) << 2))];
    }
    float bias = b2[wv * 16 + lr];
#pragma unroll 1
    for (int mt = 0; mt < 8; ++mt) {
        int ar = mt * 16 + lr;
        f32x4 acc;
        acc[0] = bias; acc[1] = bias; acc[2] = bias; acc[3] = bias;
#pragma unroll
        for (int ks = 0; ks < 4; ++ks) {
            bf16x8 a = *(const bf16x8*)&sA[ar * 64 + ((ks * 16 + q * 4) ^ ((ar & 7) << 2))];
            acc = __builtin_amdgcn_mfma_f32_16x16x32_bf16(a, bf[ks], acc, 0, 0, 0);
        }
        int col = wv * 16 + lr;
#pragma unroll
        for (int i = 0; i < 4; ++i) {
            long row = base + mt * 16 + q * 4 + i;
            if (row < (long)n) {
                if (dorelu) {
                    float v = fmaxf(acc[i], 0.f);
                    unsigned hv = f2bf(v);
                    unsigned ov = (unsigned)__shfl_xor((int)hv, 1, 64);
                    if ((lr & 1) == 0)
                        *(unsigned*)(hb + row * 64 + (col & ~1)) = hv | (ov << 16);
                } else {
                    hout[row * 64 + col] = acc[i];
                }
            } else if (dorelu) {
                // keep shfl_xor uniform across the wave
                (void)__shfl_xor((int)0, 1, 64);
            }
        }
    }
}

// ---------------- Head ----------------

__global__ __launch_bounds__(64) void k_head(const float* __restrict__ h,
        const int* __restrict__ gptr,
        const float* __restrict__ W1, const float* __restrict__ b1,
        const float* __restrict__ W2, const float* __restrict__ b2,
        float* __restrict__ out) {
    int g = blockIdx.x;
    int lane = threadIdx.x;
    int beg = gptr[g], end = gptr[g + 1];
    float s = 0.f;
    for (int r = beg; r < end; ++r) s += h[(long)r * 64 + lane];
    __shared__ float sg[64];
    sg[lane] = s;
    __syncthreads();
    float acc = b1[lane];
    for (int k = 0; k < 64; k++) acc += sg[k] * W1[k * 64 + lane];
    acc = fmaxf(acc, 0.f);
    float v = acc * W2[lane];
#pragma unroll
    for (int off = 32; off > 0; off >>= 1) v += __shfl_down(v, off, 64);
    if (lane == 0) out[g] = v + b2[0];
}

// ---------------- launch ----------------

extern "C" void kernel_launch(void* const* d_in, const int* in_sizes, int n_in,
                              void* d_out, int out_size, void* d_ws, size_t ws_size,
                              hipStream_t stream) {
    const float* x      = (const float*)d_in[0];
    const float* ea     = (const float*)d_in[1];
    const int*   ei     = (const int*)d_in[2];
    const int*   batch  = (const int*)d_in[3];
    const float* atomW1 = (const float*)d_in[4];
    const float* atomb1 = (const float*)d_in[5];
    const float* atomW2 = (const float*)d_in[6];
    const float* atomb2 = (const float*)d_in[7];
    const float* bondW1 = (const float*)d_in[8];
    const float* bondb1 = (const float*)d_in[9];
    const float* bondW2 = (const float*)d_in[10];
    const float* bondb2 = (const float*)d_in[11];
    const float* convT  = (const float*)d_in[12];
    const float* convW1 = (const float*)d_in[13];
    const float* convb1 = (const float*)d_in[14];
    const float* convG  = (const float*)d_in[15];
    const float* convBt = (const float*)d_in[16];
    const float* convW2 = (const float*)d_in[17];
    const float* convb2 = (const float*)d_in[18];
    const float* lin1W  = (const float*)d_in[19];
    const float* lin1b  = (const float*)d_in[20];
    const float* lin2W  = (const float*)d_in[21];
    const float* lin2b  = (const float*)d_in[22];
    float* out = (float*)d_out;

    const int N = in_sizes[0] / 32;
    const int E = in_sizes[1] / 16;
    const int G = out_size;
    const int Lconv = in_sizes[12];
    const int nchunk = (N + 1023) / 1024;
    const int nblk128 = (N + 127) / 128;
    const int NS64 = (N + 63) / 64;
    const int nchE2 = (E + ECH2 - 1) / ECH2;
    const size_t nquad = (size_t)((E + 3) / 4);

    size_t need = 0;
    auto count = [&](size_t bytes) { need += (bytes + 255) & ~(size_t)255; };
    count(nquad * 4 * 64 * 2);            // e_q
    count((size_t)N * 64 * 4);            // h_cur (final layer only)
    count((size_t)N * 64 * 2);            // h_bf
    count((size_t)N * 64 * 2);            // y_bf
    count((size_t)N * 128 * 2);           // h1b
    count((size_t)E * 8);                 // spe
    count((size_t)E * 8);                 // staging
    count((size_t)(N + 1) * 4);
    count((size_t)N * 4);                 // counts
    count((size_t)N * 4);                 // fill
    count(256);                           // bfill
    count((size_t)(G + 1) * 4);
    count((size_t)nblk128 * 256 * 4);     // part
    count((size_t)64 * 256 * 4);          // part2
    count(128 * 4); count(128 * 4);
    count((size_t)(nchunk + 1) * 4);
    count(4);
    count(1024 * 2);
    count(4096 * 2);
    count((size_t)Lconv * 8192 * 2);
    count((size_t)Lconv * 8192 * 2);
    if (ws_size < need) {
        hipMemsetAsync(d_out, 0, (size_t)out_size * 4, stream);
        return;
    }

    char* ws = (char*)d_ws;
    size_t off = 0;
    auto alloc = [&](size_t bytes) -> void* {
        void* p = ws + off;
        off += (bytes + 255) & ~(size_t)255;
        return p;
    };
    unsigned short* e_q = (unsigned short*)alloc(nquad * 4 * 64 * 2);
    float* h_cur    = (float*)alloc((size_t)N * 64 * 4);
    unsigned short* h_bf = (unsigned short*)alloc((size_t)N * 64 * 2);
    unsigned short* y_bf = (unsigned short*)alloc((size_t)N * 64 * 2);
    unsigned short* h1b  = (unsigned short*)alloc((size_t)N * 128 * 2);
    int2*  spe      = (int2*)alloc((size_t)E * 8);
    unsigned long long* staging = (unsigned long long*)alloc((size_t)E * 8);
    int*   row_ptr  = (int*)alloc((size_t)(N + 1) * 4);
    int*   counts   = (int*)alloc((size_t)N * 4);
    int*   fill     = (int*)alloc((size_t)N * 4);
    int*   bfill    = (int*)alloc(256);
    int*   gptr     = (int*)alloc((size_t)(G + 1) * 4);
    float* part     = (float*)alloc((size_t)nblk128 * 256 * 4);
    float* part2    = (float*)alloc((size_t)64 * 256 * 4);
    float* bnscale  = (float*)alloc(128 * 4);
    float* bnshift  = (float*)alloc(128 * 4);
    int*   csum     = (int*)alloc((size_t)(nchunk + 1) * 4);
    int*   totalp   = (int*)alloc(4);
    unsigned short* W1b  = (unsigned short*)alloc(1024 * 2);
    unsigned short* W2tb = (unsigned short*)alloc(4096 * 2);
    unsigned short* cW1tb = (unsigned short*)alloc((size_t)Lconv * 8192 * 2);
    unsigned short* cW2tb = (unsigned short*)alloc((size_t)Lconv * 8192 * 2);
    (void)n_in;

    hipMemsetAsync(counts, 0, (size_t)N * 4, stream);
    hipMemsetAsync(fill, 0, (size_t)N * 4, stream);
    hipMemsetAsync(bfill, 0, 256, stream);

    const int* src = ei;
    const int* dst = ei + E;

    k_hist<<<(E + 255) / 256, 256, 0, stream>>>(dst, counts, E);
    k_scan1<<<nchunk, 1024, 0, stream>>>(counts, row_ptr, csum, N);
    k_scan2<<<1, 64, 0, stream>>>(csum, nchunk, totalp);
    k_scan3<<<(N + 255) / 256, 256, 0, stream>>>(row_ptr, csum, totalp, N);
    k_part<<<nchE2, 256, 0, stream>>>(src, dst, row_ptr, bfill, staging, E, NS64, N);
    k_scat2<<<128, 256, 0, stream>>>(staging, row_ptr, fill, spe, NS64, N);
    k_gptr<<<(N + 256) / 256, 256, 0, stream>>>(batch, gptr, N, G);
    k_wt<<<16, 256, 0, stream>>>(bondW1, bondW2, W1b, W2tb);
    k_wtc<<<(Lconv * 8192 + 255) / 256, 256, 0, stream>>>(convW1, convW2, cW1tb, cW2tb, Lconv);

    k_atom<<<(N + TM - 1) / TM, 256, 0, stream>>>(x, atomW1, atomb1, atomW2, atomb2, h_bf, N);
    k_bond<<<(E + 127) / 128, 256, 0, stream>>>(ea, spe, W1b, bondb1, W2tb, bondb2, e_q, E);

    for (int l = 0; l < Lconv; ++l) {
        k_agg<<<(N + 3) / 4, 256, 0, stream>>>(h_bf, e_q, spe, row_ptr, convT, l, y_bf, N);
        k_gemm1<<<nblk128, 256, 0, stream>>>((const unsigned*)y_bf,
                                             (const unsigned*)(cW1tb + (size_t)l * 8192),
                                             convb1 + (size_t)l * 128,
                                             (unsigned*)h1b, part, N);
        k_bnred<<<64, 256, 0, stream>>>(part, part2, nblk128);
        k_bnfin<<<1, 1024, 0, stream>>>(part2, convG + (size_t)l * 128, convBt + (size_t)l * 128,
                                        bnscale, bnshift, 1.0f / (float)N);
        k_gemm2<<<nblk128, 256, 0, stream>>>((const unsigned*)h1b, bnscale, bnshift,
                                             (const unsigned*)(cW2tb + (size_t)l * 8192),
                                             convb2 + (size_t)l * 64, h_cur, h_bf, N,
                                             (l < Lconv - 1) ? 1 : 0);
    }

    k_head<<<G, 64, 0, stream>>>(h_cur, gptr, lin1W, lin1b, lin2W, lin2b, out);
}